// Round 4
// baseline (2057.300 us; speedup 1.0000x reference)
//
#include <hip/hip_runtime.h>
#include <hip/hip_bf16.h>

#define HW 9216      // 96*96
#define PIX 8        // pixels per final block

// Module-global intermediates (BSS, ~10 MB total) — no d_ws dependence.
__device__ float g_o1[4*32*HW];      // conv1 output (relu), fp32
__device__ float g_o2[4*26*HW];      // conv2 output (flow fields), fp32
__device__ float g_wp[96*1248*3];    // packed 1x1 weights {update,reset,out}

// ---------------- K0: pack the three 1x1-conv weight matrices, interleaved
__global__ void pack_w_k(const float* __restrict__ uw, const float* __restrict__ rw,
                         const float* __restrict__ vw){
  int i = blockIdx.x*256 + threadIdx.x;
  if (i < 96*1248){
    g_wp[i*3+0] = uw[i];
    g_wp[i*3+1] = rw[i];
    g_wp[i*3+2] = vw[i];
  }
}

// ---------------- K1: conv 5x5 pad2, in = concat(x[8], prev_state[96]), out 32 ch, relu
__global__ void conv1_k(const float* __restrict__ x, const float* __restrict__ hp,
                        const float* __restrict__ w1, const float* __restrict__ b1){
  int p  = blockIdx.x*256 + threadIdx.x;   // 0..9215
  int oc = blockIdx.y;                     // 0..31
  int b  = blockIdx.z;                     // 0..3
  int h = p / 96, w = p % 96;
  float acc = b1[oc];
  const float* wq = w1 + oc*104*25;        // (32,104,5,5)
  const float* xb = x  + b*8*HW;
  const float* hb = hp + b*96*HW;
  for (int ky = 0; ky < 5; ky++){
    int r = h + ky - 2;
    if ((unsigned)r >= 96u) continue;
    for (int kx = 0; kx < 5; kx++){
      int c = w + kx - 2;
      if ((unsigned)c >= 96u) continue;
      int off = r*96 + c;
      int wo  = ky*5 + kx;
      const float* xp  = xb + off;
      const float* wp0 = wq + wo;
      #pragma unroll
      for (int ic = 0; ic < 8; ic++)
        acc += xp[ic*HW] * wp0[ic*25];
      const float* pp  = hb + off;
      const float* wp1 = wq + 8*25 + wo;
      #pragma unroll 8
      for (int ic = 0; ic < 96; ic++)
        acc += pp[ic*HW] * wp1[ic*25];
    }
  }
  g_o1[(b*32 + oc)*HW + p] = fmaxf(acc, 0.f);
}

// ---------------- K2: conv 5x5 pad2, in 32 ch, out 26 ch, relu
__global__ void conv2_k(const float* __restrict__ w2, const float* __restrict__ b2){
  int p  = blockIdx.x*256 + threadIdx.x;
  int oc = blockIdx.y;                     // 0..25
  int b  = blockIdx.z;
  int h = p / 96, w = p % 96;
  float acc = b2[oc];
  const float* wq = w2 + oc*32*25;         // (26,32,5,5)
  const float* ib = g_o1 + b*32*HW;
  for (int ky = 0; ky < 5; ky++){
    int r = h + ky - 2;
    if ((unsigned)r >= 96u) continue;
    for (int kx = 0; kx < 5; kx++){
      int c = w + kx - 2;
      if ((unsigned)c >= 96u) continue;
      int off = r*96 + c;
      int wo  = ky*5 + kx;
      #pragma unroll 8
      for (int ic = 0; ic < 32; ic++)
        acc += ib[ic*HW + off] * wq[ic*25 + wo];
    }
  }
  g_o2[(b*26 + oc)*HW + p] = fmaxf(acc, 0.f);
}

// ---------------- K3: grid-sample (z-folded bilinear) + fused 3x3 convs on x
//                     + 1x1 GEMMs + gating
__global__ __launch_bounds__(128) void final_k(const float* __restrict__ x,
                        const float* __restrict__ hp,
                        const float* __restrict__ uw, const float* __restrict__ ub,
                        const float* __restrict__ rw, const float* __restrict__ rb,
                        const float* __restrict__ vw, const float* __restrict__ vb,
                        const float* __restrict__ uwb, const float* __restrict__ rwb,
                        const float* __restrict__ vwb, float* __restrict__ out){
  __shared__ float Msh[PIX*1248];
  __shared__ float cwgt[PIX][13][4];
  __shared__ int   coff[PIX][13][4];
  __shared__ float xs[8][3][10];           // x patch: [ic][row h-1..h+1][col w0-1..w0+8]

  int gblk = blockIdx.x;                   // 0..4607
  int b  = gblk / (HW/PIX);                // 1152 groups per batch
  int p0 = (gblk % (HW/PIX)) * PIX;        // multiple of 8 -> whole group in one row
  int t  = threadIdx.x;
  int h  = p0 / 96, w0 = p0 % 96;

  // Phase A0: stage x patch (8 ch x 3 rows x 10 cols) with zero-pad
  for (int i = t; i < 8*3*10; i += 128){
    int ic = i / 30, rem = i % 30;
    int ry = rem / 10, cx = rem % 10;
    int r = h + ry - 1, c = w0 + cx - 1;
    float v = 0.f;
    if ((unsigned)r < 96u && (unsigned)c < 96u)
      v = x[(b*8 + ic)*HW + r*96 + c];
    xs[ic][ry][cx] = v;
  }

  // Phase A1: per (pixel, l) corner weights & offsets
  if (t < PIX*13){
    int pi = t / 13, l = t % 13;
    int p = p0 + pi;
    float gx = g_o2[(b*26 + l     )*HW + p];
    float gy = g_o2[(b*26 + 13 + l)*HW + p];
    float ix = gx * (96.f/95.f) - 0.5f;
    float iy = gy * (96.f/95.f) - 0.5f;
    float iz = (float)(l+1) * (13.f/12.f) - 0.5f;
    float z0 = floorf(iz);
    float zf = 0.f;
    #pragma unroll
    for (int dz = 0; dz < 2; dz++){
      float zc = z0 + (float)dz;
      float wz = 1.f - fabsf(iz - zc);
      if (zc >= 0.f && zc <= 12.f) zf += wz;
    }
    float x0 = floorf(ix), y0 = floorf(iy);
    #pragma unroll
    for (int dy = 0; dy < 2; dy++){
      float yc = y0 + (float)dy;
      float wy = 1.f - fabsf(iy - yc);
      bool  my = (yc >= 0.f) && (yc <= 95.f);
      int  yci = min(max((int)yc, 0), 95);
      #pragma unroll
      for (int dx = 0; dx < 2; dx++){
        float xc = x0 + (float)dx;
        float wx = 1.f - fabsf(ix - xc);
        bool  mx = (xc >= 0.f) && (xc <= 95.f);
        int  xci = min(max((int)xc, 0), 95);
        cwgt[pi][l][dy*2+dx] = (mx && my) ? zf*wy*wx : 0.f;
        coff[pi][l][dy*2+dx] = yci*96 + xci;
      }
    }
  }
  __syncthreads();

  // Phase B: M[pi][c*13+l] = sum_j w_j * ps[b,c,off_j]
  const float* hb = hp + b*96*HW;
  for (int pi = 0; pi < PIX; pi++){
    for (int kk = t; kk < 1248; kk += 128){
      int c = kk / 13;
      int l = kk - c*13;
      const float* pp = hb + c*HW;
      float m = 0.f;
      #pragma unroll
      for (int j = 0; j < 4; j++)
        m += cwgt[pi][l][j] * pp[coff[pi][l][j]];
      Msh[pi*1248 + kk] = m;
    }
  }
  __syncthreads();

  // Phase C: 1x1 GEMMs (K=1248, split V accumulators) + fused 3x3 conv + gating
  if (t < 96){
    int oc = t;
    float aU[PIX], aR[PIX], aVg[PIX];      // aVg: 1x1-gemm part of v (gets reset-scaled)
    #pragma unroll
    for (int pi = 0; pi < PIX; pi++){ aU[pi] = 0.f; aR[pi] = 0.f; aVg[pi] = 0.f; }

    const float* wrow = g_wp + oc*1248*3;
    for (int k = 0; k < 1248; k++){
      float wu = wrow[k*3+0];
      float wr = wrow[k*3+1];
      float wv = wrow[k*3+2];
      #pragma unroll
      for (int pi = 0; pi < PIX; pi++){
        float m = Msh[pi*1248 + k];
        aU[pi] += m*wu; aR[pi] += m*wr; aVg[pi] += m*wv;
      }
    }
    float bu = uwb[oc], br = rwb[oc], bv = vwb[oc];
    #pragma unroll
    for (int pi = 0; pi < PIX; pi++){ aU[pi] += bu; aR[pi] += br; aVg[pi] += bv; }

    float xU[PIX], xR[PIX], xV[PIX];
    #pragma unroll
    for (int g = 0; g < 3; g++){
      const float* wsel = (g == 0) ? uw : ((g == 1) ? rw : vw);
      const float* bsel = (g == 0) ? ub : ((g == 1) ? rb : vb);
      const float* wq = wsel + oc*72;      // (96,8,3,3) row for this oc
      float acc[PIX];
      float bb = bsel[oc];
      #pragma unroll
      for (int pi = 0; pi < PIX; pi++) acc[pi] = bb;
      #pragma unroll
      for (int ic = 0; ic < 8; ic++)
        #pragma unroll
        for (int ky = 0; ky < 3; ky++)
          #pragma unroll
          for (int kx = 0; kx < 3; kx++){
            float wv = wq[ic*9 + ky*3 + kx];
            #pragma unroll
            for (int pi = 0; pi < PIX; pi++)
              acc[pi] += xs[ic][ky][pi+kx] * wv;
          }
      #pragma unroll
      for (int pi = 0; pi < PIX; pi++){
        if (g == 0) xU[pi] = acc[pi];
        else if (g == 1) xR[pi] = acc[pi];
        else xV[pi] = acc[pi];
      }
    }

    #pragma unroll
    for (int pi = 0; pi < PIX; pi++){
      int p = p0 + pi;
      float u = 1.f / (1.f + expf(-(xU[pi] + aU[pi])));
      float r = 1.f / (1.f + expf(-(xR[pi] + aR[pi])));
      float v = xV[pi] + r * aVg[pi];
      float oi = (v >= 0.f) ? v : 0.2f*v;
      float h0 = hb[oc*HW + p];
      out[(b*96 + oc)*HW + p] = h0*u + oi*(1.f - u);
    }
  }
}

extern "C" void kernel_launch(void* const* d_in, const int* in_sizes, int n_in,
                              void* d_out, int out_size, void* d_ws, size_t ws_size,
                              hipStream_t stream){
  const float* x    = (const float*)d_in[0];
  const float* hp   = (const float*)d_in[1];
  const float* sw1  = (const float*)d_in[2];
  const float* sb1  = (const float*)d_in[3];
  const float* sw2  = (const float*)d_in[4];
  const float* sb2  = (const float*)d_in[5];
  const float* rw   = (const float*)d_in[6];
  const float* rb   = (const float*)d_in[7];
  const float* uw   = (const float*)d_in[8];
  const float* ub   = (const float*)d_in[9];
  const float* vw   = (const float*)d_in[10];
  const float* vb   = (const float*)d_in[11];
  const float* rww  = (const float*)d_in[12];
  const float* rwb  = (const float*)d_in[13];
  const float* uww  = (const float*)d_in[14];
  const float* uwb  = (const float*)d_in[15];
  const float* vww  = (const float*)d_in[16];
  const float* vwb  = (const float*)d_in[17];

  pack_w_k<<<dim3((96*1248 + 255)/256), dim3(256), 0, stream>>>(uww, rww, vww);
  conv1_k <<<dim3(HW/256, 32, 4), dim3(256), 0, stream>>>(x, hp, sw1, sb1);
  conv2_k <<<dim3(HW/256, 26, 4), dim3(256), 0, stream>>>(sw2, sb2);
  final_k <<<dim3(4*HW/PIX), dim3(128), 0, stream>>>(x, hp,
            uw, ub, rw, rb, vw, vb, uwb, rwb, vwb, (float*)d_out);
}